// Round 2
// baseline (4257.180 us; speedup 1.0000x reference)
//
#include <hip/hip_runtime.h>
#include <hip/hip_bf16.h>

#define THREADS 448

// Geometry constants (from reference):
// comb2: [2][128][32][32][32]  (ch stride 32768, z 1024, y 32)
// out1 : [2][64][64][64][64]   (ch stride 262144, z 4096, y 64)
// proposals: [N][7] = (b, z0,y0,x0, z1,y1,x1), extent 28 -> 7 @/4, 14 @/2
// output: [N][64][7][7][7]

__device__ __forceinline__ void interp14(int o, int& i0, int& i1, float& w) {
    // align_corners=True, 7 -> 14: src = o * (s-1)/(o-1) = o * 6/13
    float src = (float)o * (6.0f / 13.0f);
    int f = (int)src;            // src >= 0 -> trunc == floor
    if (f > 6) f = 6;
    i0 = f;
    i1 = (f + 1 > 6) ? 6 : f + 1;
    w = src - (float)f;
}

// z/y lerp of one x-row (7 wide) from y1 (stored [64][353] in LDS)
__device__ __forceinline__ void lerp_rows(const float* Yc, int oz, int oy, float* row) {
    int iz0, iz1; float wz; interp14(oz, iz0, iz1, wz);
    int iy0, iy1; float wy; interp14(oy, iy0, iy1, wy);
    const float* p00 = Yc + iz0 * 49 + iy0 * 7;
    const float* p01 = Yc + iz1 * 49 + iy0 * 7;
    const float* p10 = Yc + iz0 * 49 + iy1 * 7;
    const float* p11 = Yc + iz1 * 49 + iy1 * 7;
#pragma unroll
    for (int x = 0; x < 7; ++x) {
        float a = p00[x] + (p01[x] - p00[x]) * wz;
        float b = p10[x] + (p11[x] - p10[x]) * wz;
        row[x] = a + (b - a) * wy;
    }
}

__device__ __forceinline__ float xsample(const float* row, int ox_i0, int ox_i1, float wx) {
    return row[ox_i0] + (row[ox_i1] - row[ox_i0]) * wx;
}

template <int PASS>
__device__ __forceinline__ void stage2_pass(
    int t, int n,
    const float* __restrict__ Wb, const float* __restrict__ bb,
    const float* __restrict__ gb, const float* __restrict__ beb,
    const float* __restrict__ o1base,
    const float* sY, __hip_bfloat16* sF,
    const float* sScale1, const float* sShift1,
    float* sScale2, float* sShift2, float* sRed,
    float* __restrict__ out)
{
    float sum[64], sq[64];
    if (PASS == 0) {
#pragma unroll
        for (int c = 0; c < 64; ++c) { sum[c] = 0.f; sq[c] = 0.f; }
    }

    for (int pz = 0; pz < 7; ++pz) {
        __syncthreads();   // previous conv done reading sF
        // ---- build fe1n slab (normalized+relu branch-1 values) for oz in {2pz, 2pz+1}
        // custom voxel order: v = cell*8 + corner, cell=(oy>>1)*7+(ox>>1),
        // corner = dz*4 + (oy&1)*2 + (ox&1)  -> 2x2x2 pool groups are 8 consecutive lanes
        for (int task = t; task < 64 * 28; task += THREADS) {
            int c = task & 63, rr = task >> 6;        // rr in [0,28)
            int dz = rr / 14, oy = rr - dz * 14;
            int oz = 2 * pz + dz;
            float row[7];
            lerp_rows(sY + c * 353, oz, oy, row);
            float sc = sScale1[c], sh = sShift1[c];
#pragma unroll
            for (int ox = 0; ox < 14; ++ox) {
                int i0, i1; float wx; interp14(ox, i0, i1, wx);  // constant-folded
                float u = xsample(row, i0, i1, wx);
                float v = fmaxf(fmaf(u, sc, sh), 0.f);
                int cell = (oy >> 1) * 7 + (ox >> 1);
                int corner = (dz << 2) | ((oy & 1) << 1) | (ox & 1);
                sF[c * 402 + cell * 8 + corner] = __float2bfloat16(v);
            }
        }
        __syncthreads();

        // ---- conv2 (1x1, 64x128) at the 392 voxels of this slice pair
        if (t < 392) {
            int corner = t & 7, cell = t >> 3;
            int dz = corner >> 2, dy = (corner >> 1) & 1, dx = corner & 1;
            int py = cell / 7, px = cell - py * 7;
            int oz = 2 * pz + dz, oy = 2 * py + dy, ox = 2 * px + dx;
            const float* o1p = o1base + (size_t)(oz * 4096 + oy * 64 + ox);

            float acc[64];
#pragma unroll
            for (int co = 0; co < 64; ++co) acc[co] = bb[co];

            // first 64 input channels: normalized branch-1 from LDS slab
            for (int c0 = 0; c0 < 64; c0 += 8) {
                float f[8];
#pragma unroll
                for (int k = 0; k < 8; ++k) f[k] = __bfloat162float(sF[(c0 + k) * 402 + t]);
#pragma unroll
                for (int co = 0; co < 64; ++co) {
#pragma unroll
                    for (int k = 0; k < 8; ++k)
                        acc[co] = fmaf(Wb[co * 128 + c0 + k], f[k], acc[co]);
                }
            }
            // second 64 input channels: raw out1 slice from global (L2/L3 resident)
            for (int c0 = 0; c0 < 64; c0 += 8) {
                float f[8];
#pragma unroll
                for (int k = 0; k < 8; ++k) f[k] = o1p[(size_t)(c0 + k) * 262144];
#pragma unroll
                for (int co = 0; co < 64; ++co) {
#pragma unroll
                    for (int k = 0; k < 8; ++k)
                        acc[co] = fmaf(Wb[co * 128 + 64 + c0 + k], f[k], acc[co]);
                }
            }

            if (PASS == 0) {
#pragma unroll
                for (int co = 0; co < 64; ++co) { sum[co] += acc[co]; sq[co] += acc[co] * acc[co]; }
            } else {
#pragma unroll
                for (int co = 0; co < 64; ++co) {
                    float v = fmaxf(fmaf(acc[co], sScale2[co], sShift2[co]), 0.f);
                    // 2x2x2 maxpool across the 8-lane corner group
                    v = fmaxf(v, __shfl_xor(v, 1));
                    v = fmaxf(v, __shfl_xor(v, 2));
                    v = fmaxf(v, __shfl_xor(v, 4));
                    if (corner == 0)
                        out[((size_t)n * 64 + co) * 343 + pz * 49 + py * 7 + px] = v;
                }
            }
        }
    }

    if (PASS == 0) {
        // reduce per-thread partial stats -> per-channel scale2/shift2
        int wave = t >> 6, lane = t & 63;
#pragma unroll
        for (int co = 0; co < 64; ++co) {
            float s = sum[co], q = sq[co];
            for (int off = 32; off; off >>= 1) {
                s += __shfl_down(s, off);
                q += __shfl_down(q, off);
            }
            if (lane == 0) { sRed[(wave * 64 + co) * 2 + 0] = s; sRed[(wave * 64 + co) * 2 + 1] = q; }
        }
        __syncthreads();
        if (t < 64) {
            float S = 0.f, Q = 0.f;
#pragma unroll
            for (int w = 0; w < 7; ++w) { S += sRed[(w * 64 + t) * 2 + 0]; Q += sRed[(w * 64 + t) * 2 + 1]; }
            float mean = S * (1.0f / 2744.0f);
            float var  = Q * (1.0f / 2744.0f) - mean * mean;
            float sc = gb[t] * rsqrtf(var + 1e-5f);
            sScale2[t] = sc;
            sShift2[t] = beb[t] - mean * sc;
        }
        __syncthreads();
    }
}

__global__ __launch_bounds__(THREADS, 2)
void crop_roi_kernel(const float* __restrict__ out1,
                     const float* __restrict__ comb2,
                     const int* __restrict__ props,
                     const float* __restrict__ W_up2, const float* __restrict__ b_up2,
                     const float* __restrict__ g_up2, const float* __restrict__ be_up2,
                     const float* __restrict__ W_back2, const float* __restrict__ b_back2,
                     const float* __restrict__ g_back2, const float* __restrict__ be_back2,
                     const int* __restrict__ cls_ind,
                     float* __restrict__ out)
{
    extern __shared__ unsigned char smem[];
    float* sY = (float*)smem;                                    // [64][353] f32 (odd stride: no bank conflict)
    __hip_bfloat16* sF = (__hip_bfloat16*)(smem + 64 * 353 * 4); // [64][402] bf16 slab (odd 4B stride)
    float* sMisc  = (float*)(smem + 64 * 353 * 4 + 64 * 402 * 2);
    float* sScale1 = sMisc;          // 64
    float* sShift1 = sMisc + 64;     // 64
    float* sScale2 = sMisc + 128;    // 64
    float* sShift2 = sMisc + 192;    // 64
    float* sStat   = sMisc + 256;    // 128 (sum, sumsq for branch-1 stats)
    float* sRed    = sMisc + 384;    // 7*64*2 = 896

    const int t = threadIdx.x;
    const int n = blockIdx.x;
    const int cls = cls_ind[0];
    const int* P = props + n * 7;
    const int b = P[0], z0 = P[1], y0 = P[2], x0 = P[3];

    const float* Wu  = W_up2  + cls * 64 * 128;
    const float* bu  = b_up2  + cls * 64;
    const float* gu  = g_up2  + cls * 64;
    const float* beu = be_up2 + cls * 64;
    const float* Wb  = W_back2 + cls * 64 * 128;
    const float* bb  = b_back2 + cls * 64;
    const float* gb  = g_back2 + cls * 64;
    const float* beb = be_back2 + cls * 64;

    // ---- Stage 1: conv1x1 (Wu) at 7x7x7 (conv commutes with upsample) -> sY
    if (t < 343) {
        int vz = t / 49, r = t - vz * 49, vy = r / 7, vx = r - vy * 7;
        const float* src = comb2 + (size_t)b * 128 * 32768
                         + (size_t)((z0 / 4 + vz) * 1024 + (y0 / 4 + vy) * 32 + (x0 / 4 + vx));
        float acc[64];
#pragma unroll
        for (int c = 0; c < 64; ++c) acc[c] = bu[c];
        for (int ci0 = 0; ci0 < 128; ci0 += 8) {
            float f[8];
#pragma unroll
            for (int k = 0; k < 8; ++k) f[k] = src[(size_t)(ci0 + k) * 32768];
#pragma unroll
            for (int c = 0; c < 64; ++c) {
#pragma unroll
                for (int k = 0; k < 8; ++k)
                    acc[c] = fmaf(Wu[c * 128 + ci0 + k], f[k], acc[c]);
            }
        }
#pragma unroll
        for (int c = 0; c < 64; ++c) sY[c * 353 + t] = acc[c];
    }
    if (t < 128) sStat[t] = 0.f;
    __syncthreads();

    // ---- Stage 1b: per-channel stats of the (virtual) upsampled field u = up2(sY)
    for (int task = t; task < 64 * 196; task += THREADS) {   // 12544 / 448 = 28 exact
        int c = task & 63, rr = task >> 6;                   // lanes -> distinct c (no atomic clash)
        int oz = rr / 14, oy = rr - oz * 14;
        float row[7];
        lerp_rows(sY + c * 353, oz, oy, row);
        float s = 0.f, q = 0.f;
#pragma unroll
        for (int ox = 0; ox < 14; ++ox) {
            int i0, i1; float wx; interp14(ox, i0, i1, wx);
            float u = xsample(row, i0, i1, wx);
            s += u; q += u * u;
        }
        atomicAdd(&sStat[c], s);
        atomicAdd(&sStat[64 + c], q);
    }
    __syncthreads();
    if (t < 64) {
        float mean = sStat[t] * (1.0f / 2744.0f);
        float var  = sStat[64 + t] * (1.0f / 2744.0f) - mean * mean;
        float sc = gu[t] * rsqrtf(var + 1e-5f);
        sScale1[t] = sc;
        sShift1[t] = beu[t] - mean * sc;
    }
    __syncthreads();

    const float* o1base = out1 + (size_t)b * 64 * 262144
                        + (size_t)((z0 / 2) * 4096 + (y0 / 2) * 64 + (x0 / 2));

    // Pass A: conv2 stats; Pass B: conv2 -> norm -> relu -> maxpool -> out
    stage2_pass<0>(t, n, Wb, bb, gb, beb, o1base, sY, sF, sScale1, sShift1, sScale2, sShift2, sRed, out);
    stage2_pass<1>(t, n, Wb, bb, gb, beb, o1base, sY, sF, sScale1, sShift1, sScale2, sShift2, sRed, out);
}

extern "C" void kernel_launch(void* const* d_in, const int* in_sizes, int n_in,
                              void* d_out, int out_size, void* d_ws, size_t ws_size,
                              hipStream_t stream)
{
    const float* out1    = (const float*)d_in[1];
    const float* comb2   = (const float*)d_in[2];
    const int*   props   = (const int*)d_in[4];
    const float* W_up2   = (const float*)d_in[5];
    const float* b_up2   = (const float*)d_in[6];
    const float* g_up2   = (const float*)d_in[7];
    const float* be_up2  = (const float*)d_in[8];
    const float* W_back2 = (const float*)d_in[9];
    const float* b_back2 = (const float*)d_in[10];
    const float* g_back2 = (const float*)d_in[11];
    const float* be_back2= (const float*)d_in[12];
    const int*   cls     = (const int*)d_in[13];
    float* out = (float*)d_out;

    int nprop = in_sizes[4] / 7;   // 512
    size_t smem = (size_t)64 * 353 * 4 + (size_t)64 * 402 * 2 + (size_t)1280 * 4; // 146944 B

    crop_roi_kernel<<<nprop, THREADS, smem, stream>>>(
        out1, comb2, props, W_up2, b_up2, g_up2, be_up2,
        W_back2, b_back2, g_back2, be_back2, cls, out);
}

// Round 3
// 1336.305 us; speedup vs baseline: 3.1858x; 3.1858x over previous
//
#include <hip/hip_runtime.h>
#include <hip/hip_bf16.h>

#define THREADS 512

typedef __attribute__((ext_vector_type(4))) float f32x4;
typedef __attribute__((ext_vector_type(8))) short short8;

// Geometry:
// comb2: [2][128][32^3]  (ch stride 32768, z 1024, y 32)
// out1 : [2][64][64^3]   (ch stride 262144, z 4096, y 64)
// proposals: [N][7] = (b, z0,y0,x0, ...), extent 28 -> 7 @/4, 14 @/2
// output: [N][64][7][7][7]
//
// LDS layout (bytes):
//   [0, 95744)        stage1 X1: [352 vox][136 ci] bf16 (stride 272B = 17*16B)
//                     -> after stage1: sY f32 [64][349] (89344 B)
//   [95744, 152320)   slice X: [208 cols][136 ci] bf16 ; pass-B reuses rows 0..48 as sOut f32 [64][52]
//   [152320, 154880)  misc floats (640)
#define OFF_X    95744
#define OFF_MISC 152320
#define SMEM_BYTES 154880

__device__ __forceinline__ unsigned short f2bf(float f) {
    union { __hip_bfloat16 h; unsigned short u; } c;
    c.h = __float2bfloat16(f);
    return c.u;
}

__device__ __forceinline__ void interp14(int o, int& i0, int& i1, float& w) {
    // align_corners=True, 7 -> 14: src = o * 6/13
    float src = (float)o * (6.0f / 13.0f);
    int f = (int)src;
    if (f > 6) f = 6;
    i0 = f;
    i1 = (f + 1 > 6) ? 6 : f + 1;
    w = src - (float)f;
}

// z/y lerp of one x-row (7 wide) from a [7][7][7] channel (linear vox layout)
__device__ __forceinline__ void lerp_rows(const float* Yc, int oz, int oy, float* row) {
    int iz0, iz1; float wz; interp14(oz, iz0, iz1, wz);
    int iy0, iy1; float wy; interp14(oy, iy0, iy1, wy);
    const float* p00 = Yc + iz0 * 49 + iy0 * 7;
    const float* p01 = Yc + iz1 * 49 + iy0 * 7;
    const float* p10 = Yc + iz0 * 49 + iy1 * 7;
    const float* p11 = Yc + iz1 * 49 + iy1 * 7;
#pragma unroll
    for (int x = 0; x < 7; ++x) {
        float a = p00[x] + (p01[x] - p00[x]) * wz;
        float b = p10[x] + (p11[x] - p10[x]) * wz;
        row[x] = a + (b - a) * wy;
    }
}

__device__ __forceinline__ float xsample(const float* row, int i0, int i1, float wx) {
    return row[i0] + (row[i1] - row[i0]) * wx;
}

// Build one z-slice (196 voxels) of X = [fe1n(0..63); o1(64..127)] into sx.
// Column order: col = ((oy>>1)*7 + (ox>>1))*4 + (oy&1)*2 + (ox&1)  (pool quads = 4 consecutive cols)
__device__ __forceinline__ void build_slice(
    int t, int oz, int b, int hz0, int hy0, int hx0,
    const float* __restrict__ out1,
    const float* sY, const float* sA1, const float* sSh1, char* sx)
{
    // o1 half (ci 64..127): tasks (ch, oy) = 896, rows of 14 f32 (float2-aligned since hx0 even)
    const float* o1b = out1 + (size_t)b * 64 * 262144
                     + (size_t)(hz0 + oz) * 4096 + hy0 * 64 + hx0;
    for (int idx = t; idx < 896; idx += THREADS) {
        int oy = idx % 14;
        int ch = idx / 14;
        const float* p = o1b + (size_t)ch * 262144 + oy * 64;
        int cb = (oy >> 1) * 28 + (oy & 1) * 2;
        char* dst = sx + 128 + 2 * ch;
#pragma unroll
        for (int oxp = 0; oxp < 7; ++oxp) {
            float2 f = *(const float2*)(p + 2 * oxp);
            int col0 = cb + oxp * 4;
            *(unsigned short*)(dst + (size_t)col0 * 272)       = f2bf(f.x);
            *(unsigned short*)(dst + (size_t)(col0 + 1) * 272) = f2bf(f.y);
        }
    }
    // fe1n half (ci 0..63): tasks (c2 in [0,32), oy in [0,14)) -> t < 448
    if (t < 448) {
        int c2 = t & 31, oy = t >> 5;
        int c0 = 2 * c2;
        float row0[7], row1[7];
        lerp_rows(sY + c0 * 349, oz, oy, row0);
        lerp_rows(sY + (c0 + 1) * 349, oz, oy, row1);
        float a0 = sA1[c0],   s0 = sSh1[c0];
        float a1v = sA1[c0 + 1], s1 = sSh1[c0 + 1];
        char* dst = sx + 4 * c2;
        int cb = (oy >> 1) * 28 + (oy & 1) * 2;
#pragma unroll
        for (int ox = 0; ox < 14; ++ox) {
            int i0, i1; float wx; interp14(ox, i0, i1, wx);
            float u0 = xsample(row0, i0, i1, wx);
            float u1 = xsample(row1, i0, i1, wx);
            unsigned v = (unsigned)f2bf(fmaxf(fmaf(u0, a0, s0), 0.f))
                       | ((unsigned)f2bf(fmaxf(fmaf(u1, a1v, s1), 0.f)) << 16);
            int col = cb + (ox >> 1) * 4 + (ox & 1);
            *(unsigned*)(dst + (size_t)col * 272) = v;
        }
    }
}

__global__ __launch_bounds__(THREADS, 1)
void crop_roi_mfma(const float* __restrict__ out1,
                   const float* __restrict__ comb2,
                   const int* __restrict__ props,
                   const float* __restrict__ W_up2,
                   const float* __restrict__ g_up2, const float* __restrict__ be_up2,
                   const float* __restrict__ W_back2,
                   const float* __restrict__ g_back2, const float* __restrict__ be_back2,
                   const int* __restrict__ cls_ind,
                   float* __restrict__ out)
{
    extern __shared__ char smem[];
    char*  sx1   = smem;                       // stage1 X1 [352][136] bf16
    float* sY    = (float*)smem;               // later: conv1 output [64][349] f32
    char*  sx    = smem + OFF_X;               // slice X [208][136] bf16
    float* sOutF = (float*)(smem + OFF_X);     // pass-B staging [64][52] f32
    float* sM    = (float*)(smem + OFF_MISC);
    float* sStat1 = sM;         // 128
    float* sA1    = sM + 128;   // 64
    float* sSh1   = sM + 192;   // 64
    float* sSumB  = sM + 256;   // 128
    float* sSqB   = sM + 384;   // 128
    float* sA2    = sM + 512;   // 64
    float* sSh2   = sM + 576;   // 64

    const int t = threadIdx.x;
    const int l = t & 63;
    const int w = t >> 6;
    const int mr = w & 3;          // M row-tile: co 16*mr .. 16*mr+15
    const int h  = w >> 2;         // column half
    const int n = blockIdx.x;
    const int cls = cls_ind[0];

    const int* P = props + n * 7;
    const int b = P[0], z0 = P[1], y0 = P[2], x0 = P[3];
    const int qz0 = z0 >> 2, qy0 = y0 >> 2, qx0 = x0 >> 2;
    const int hz0 = z0 >> 1, hy0 = y0 >> 1, hx0 = x0 >> 1;

    // ---- zero pad regions (X1 rows 343..351, X cols 196..207) + stat accumulators
    {
        unsigned* p1 = (unsigned*)(sx1 + 343 * 272);
        for (int i = t; i < 9 * 68; i += THREADS) p1[i] = 0;
        unsigned* p2 = (unsigned*)(sx + 196 * 272);
        for (int i = t; i < 12 * 68; i += THREADS) p2[i] = 0;
        if (t < 128) sStat1[t] = 0.f;
    }

    // ---- build X1 from comb2 crop (f32 gather -> bf16, voxel-major)
    {
        const float* base = comb2 + (size_t)b * 128 * 32768;
        for (int idx = t; idx < 6272; idx += THREADS) {
            int r  = idx % 49;           // vz*7+vy
            int ci = idx / 49;
            int vz = r / 7, vy = r - vz * 7;
            const float* p = base + (size_t)ci * 32768
                           + (qz0 + vz) * 1024 + (qy0 + vy) * 32 + qx0;
            char* dst = sx1 + (size_t)(r * 7) * 272 + 2 * ci;
#pragma unroll
            for (int vx = 0; vx < 7; ++vx)
                *(unsigned short*)(dst + (size_t)vx * 272) = f2bf(p[vx]);
        }
    }

    // ---- A-fragments: Wu (lane l: row = l&15, k = 32s + 8*(l>>4) + j)
    short8 aw[4];
    {
        const float* Wg = W_up2 + (size_t)cls * 8192 + (size_t)(16 * mr + (l & 15)) * 128 + 8 * (l >> 4);
#pragma unroll
        for (int s = 0; s < 4; ++s) {
            short8 v;
#pragma unroll
            for (int j = 0; j < 8; ++j) v[j] = (short)f2bf(Wg[32 * s + j]);
            aw[s] = v;
        }
    }
    __syncthreads();

    const int bl = (l & 15) * 272 + 16 * (l >> 4);

    // ---- stage1 MFMA: Y1[64][343] = Wu x X1 (22 col-tiles, halves 11/11)
    {
        f32x4 acc1[11];
#pragma unroll
        for (int k = 0; k < 11; ++k) acc1[k] = (f32x4){0.f, 0.f, 0.f, 0.f};
#pragma unroll
        for (int s = 0; s < 4; ++s) {
#pragma unroll
            for (int k = 0; k < 11; ++k) {
                int nc = 11 * h + k;
                short8 bf = *(const short8*)(sx1 + (size_t)nc * 4352 + bl + 64 * s);
                acc1[k] = __builtin_amdgcn_mfma_f32_16x16x32_bf16(aw[s], bf, acc1[k], 0, 0, 0);
            }
        }
        __syncthreads();   // all X1 reads done -> safe to overwrite region with sY
#pragma unroll
        for (int k = 0; k < 11; ++k) {
            int vox = 16 * (11 * h + k) + (l & 15);
            if (vox < 343) {
#pragma unroll
                for (int i = 0; i < 4; ++i)
                    sY[(16 * mr + 4 * (l >> 4) + i) * 349 + vox] = acc1[k][i];
            }
        }
    }
    __syncthreads();

    // ---- stage1b: per-channel stats of the virtual upsampled field (bias-free; bias cancels in inorm)
    for (int idx = t; idx < 12544; idx += THREADS) {
        int c = idx & 63, rr = idx >> 6;
        int oz = rr / 14, oy = rr - oz * 14;
        float row[7];
        lerp_rows(sY + c * 349, oz, oy, row);
        float s = 0.f, q = 0.f;
#pragma unroll
        for (int ox = 0; ox < 14; ++ox) {
            int i0, i1; float wx; interp14(ox, i0, i1, wx);
            float u = xsample(row, i0, i1, wx);
            s += u; q = fmaf(u, u, q);
        }
        atomicAdd(&sStat1[c], s);
        atomicAdd(&sStat1[64 + c], q);
    }
    __syncthreads();
    if (t < 64) {
        float mean = sStat1[t] * (1.f / 2744.f);
        float var  = sStat1[64 + t] * (1.f / 2744.f) - mean * mean;
        float a = g_up2[cls * 64 + t] * rsqrtf(var + 1e-5f);
        sA1[t]  = a;
        sSh1[t] = be_up2[cls * 64 + t] - a * mean;
    }

    // ---- A-fragments: Wb (reuse regs)
    {
        const float* Wg = W_back2 + (size_t)cls * 8192 + (size_t)(16 * mr + (l & 15)) * 128 + 8 * (l >> 4);
#pragma unroll
        for (int s = 0; s < 4; ++s) {
            short8 v;
#pragma unroll
            for (int j = 0; j < 8; ++j) v[j] = (short)f2bf(Wg[32 * s + j]);
            aw[s] = v;
        }
    }
    __syncthreads();

    // ================= PASS A: conv2 stats (pad cols are zero -> contribute nothing) =================
    float sum4[4] = {0.f, 0.f, 0.f, 0.f}, sq4[4] = {0.f, 0.f, 0.f, 0.f};
    for (int oz = 0; oz < 14; ++oz) {
        __syncthreads();
        build_slice(t, oz, b, hz0, hy0, hx0, out1, sY, sA1, sSh1, sx);
        __syncthreads();
        f32x4 acc[7];
#pragma unroll
        for (int k = 0; k < 7; ++k) acc[k] = (f32x4){0.f, 0.f, 0.f, 0.f};
#pragma unroll
        for (int s = 0; s < 4; ++s) {
#pragma unroll
            for (int k = 0; k < 7; ++k) {
                int nc = 7 * h + k;
                if (nc < 13) {
                    short8 bf = *(const short8*)(sx + (size_t)nc * 4352 + bl + 64 * s);
                    acc[k] = __builtin_amdgcn_mfma_f32_16x16x32_bf16(aw[s], bf, acc[k], 0, 0, 0);
                }
            }
        }
#pragma unroll
        for (int k = 0; k < 7; ++k) {
            int nc = 7 * h + k;
            if (nc < 13) {
#pragma unroll
                for (int i = 0; i < 4; ++i) {
                    sum4[i] += acc[k][i];
                    sq4[i] = fmaf(acc[k][i], acc[k][i], sq4[i]);
                }
            }
        }
    }

    // reduce stats: shfl over the 16 column-lanes, then combine halves in LDS
    {
#pragma unroll
        for (int i = 0; i < 4; ++i) {
            float s = sum4[i], q = sq4[i];
#pragma unroll
            for (int m = 1; m < 16; m <<= 1) {
                s += __shfl_xor(s, m);
                q += __shfl_xor(q, m);
            }
            if ((l & 15) == 0) {
                int co = 16 * mr + 4 * (l >> 4) + i;
                sSumB[h * 64 + co] = s;
                sSqB [h * 64 + co] = q;
            }
        }
        __syncthreads();
        if (t < 64) {
            float S = sSumB[t] + sSumB[64 + t];
            float Q = sSqB[t] + sSqB[64 + t];
            float mean = S * (1.f / 2744.f);
            float var  = Q * (1.f / 2744.f) - mean * mean;
            float a = g_back2[cls * 64 + t] * rsqrtf(var + 1e-5f);
            sA2[t]  = a;
            sSh2[t] = be_back2[cls * 64 + t] - a * mean;
        }
        __syncthreads();
    }

    // ================= PASS B: conv2 -> norm+relu -> 2x2x2 maxpool -> out =================
    float a_r[4], sh_r[4];
#pragma unroll
    for (int i = 0; i < 4; ++i) {
        int co = 16 * mr + 4 * (l >> 4) + i;
        a_r[i]  = sA2[co];
        sh_r[i] = sSh2[co];
    }

    float pm[7][4];
    const size_t nbase = (size_t)n * 21952;
    for (int oz = 0; oz < 14; ++oz) {
        int pz = oz >> 1, par = oz & 1;
        __syncthreads();
        build_slice(t, oz, b, hz0, hy0, hx0, out1, sY, sA1, sSh1, sx);
        __syncthreads();
        f32x4 acc[7];
#pragma unroll
        for (int k = 0; k < 7; ++k) acc[k] = (f32x4){0.f, 0.f, 0.f, 0.f};
#pragma unroll
        for (int s = 0; s < 4; ++s) {
#pragma unroll
            for (int k = 0; k < 7; ++k) {
                int nc = 7 * h + k;
                if (nc < 13) {
                    short8 bf = *(const short8*)(sx + (size_t)nc * 4352 + bl + 64 * s);
                    acc[k] = __builtin_amdgcn_mfma_f32_16x16x32_bf16(aw[s], bf, acc[k], 0, 0, 0);
                }
            }
        }
        // finalize + in-plane 2x2 pool via shfl (cols are cell*4+corner)
#pragma unroll
        for (int k = 0; k < 7; ++k) {
            int nc = 7 * h + k;
            if (nc < 13) {
#pragma unroll
                for (int i = 0; i < 4; ++i) {
                    float v = fmaxf(fmaf(acc[k][i], a_r[i], sh_r[i]), 0.f);
                    v = fmaxf(v, __shfl_xor(v, 1));
                    v = fmaxf(v, __shfl_xor(v, 2));
                    pm[k][i] = par ? fmaxf(pm[k][i], v) : v;
                }
            }
        }
        if (par) {
            __syncthreads();   // all X reads done; sOutF overlays X rows 0..48
            if ((l & 3) == 0) {
#pragma unroll
                for (int k = 0; k < 7; ++k) {
                    int nc = 7 * h + k;
                    int cell = 4 * nc + ((l >> 2) & 3);
                    if (nc < 13 && cell < 49) {
#pragma unroll
                        for (int i = 0; i < 4; ++i)
                            sOutF[(16 * mr + 4 * (l >> 4) + i) * 52 + cell] = pm[k][i];
                    }
                }
            }
            __syncthreads();
            for (int idx = t; idx < 3136; idx += THREADS) {
                int co = idx / 49;
                int cell = idx - co * 49;
                out[nbase + (size_t)co * 343 + pz * 49 + cell] = sOutF[co * 52 + cell];
            }
        }
    }
}

extern "C" void kernel_launch(void* const* d_in, const int* in_sizes, int n_in,
                              void* d_out, int out_size, void* d_ws, size_t ws_size,
                              hipStream_t stream)
{
    const float* out1     = (const float*)d_in[1];
    const float* comb2    = (const float*)d_in[2];
    const int*   props    = (const int*)d_in[4];
    const float* W_up2    = (const float*)d_in[5];
    const float* g_up2    = (const float*)d_in[7];
    const float* be_up2   = (const float*)d_in[8];
    const float* W_back2  = (const float*)d_in[9];
    const float* g_back2  = (const float*)d_in[11];
    const float* be_back2 = (const float*)d_in[12];
    const int*   cls      = (const int*)d_in[13];
    float* out = (float*)d_out;

    int nprop = in_sizes[4] / 7;   // 512

    crop_roi_mfma<<<nprop, THREADS, SMEM_BYTES, stream>>>(
        out1, comb2, props, W_up2, g_up2, be_up2,
        W_back2, g_back2, be_back2, cls, out);
}